// Round 11
// baseline (932.129 us; speedup 1.0000x reference)
//
#include <hip/hip_runtime.h>
#include <math.h>

#define NN 50000
#define NE 800000

#define LRELU(v) ((v) > 0.f ? (v) : 0.2f * (v))

typedef __attribute__((ext_vector_type(4))) float f32x4;
typedef __attribute__((ext_vector_type(8))) short bf16x8;

static __device__ __forceinline__ unsigned short f2bf(float f) {
  union { float f; unsigned int i; } c; c.f = f;
  unsigned int r = c.i + 0x7fff + ((c.i >> 16) & 1);   // RNE
  return (unsigned short)(r >> 16);
}
static __device__ __forceinline__ float bflo(unsigned int u) {
  union { unsigned int i; float f; } c; c.i = u << 16; return c.f;
}
static __device__ __forceinline__ float bfhi(unsigned int u) {
  union { unsigned int i; float f; } c; c.i = u & 0xffff0000u; return c.f;
}

// ---------------------------------------------------------------------------
// conv_wf: W [K][256] fp32 -> fragment-ordered bf16 table
//   wf[((ks*16+n)*64 + l)*8 + j] = bf16(W[ks*32 + (l>>4)*8 + j][n*16 + (l&15)])
// ---------------------------------------------------------------------------
__global__ __launch_bounds__(256)
void conv_wf(const float* __restrict__ W, unsigned short* __restrict__ wf,
             int K) {
  const int g = blockIdx.x * 256 + threadIdx.x;   // K*256 total
  if (g >= K * 256) return;
  const int j = g & 7;
  const int l = (g >> 3) & 63;
  const int fn = g >> 9;
  const int n = fn & 15, ks = fn >> 4;
  const int k = ks * 32 + (l >> 4) * 8 + j;
  const int c = n * 16 + (l & 15);
  wf[g] = f2bf(W[(size_t)k * 256 + c]);
}

// ---------------------------------------------------------------------------
// MFMA node GEMM: outb = bf16(A @ W + b). No LDS; wf streamed from L2.
// ---------------------------------------------------------------------------
template <int KS>   // KS = K/32
__global__ __launch_bounds__(256)
void gemm_mfma(const float* __restrict__ A,
               const unsigned short* __restrict__ wf0,
               const float* __restrict__ b0, unsigned short* __restrict__ outb0,
               const unsigned short* __restrict__ wf1,
               const float* __restrict__ b1, unsigned short* __restrict__ outb1) {
  const unsigned short* wf = blockIdx.y ? wf1 : wf0;
  const float* bias        = blockIdx.y ? b1 : b0;
  unsigned short* outb     = blockIdx.y ? outb1 : outb0;

  const int tid = threadIdx.x;
  const int w = tid >> 6, l = tid & 63;
  const int lid = l & 15, lg = l >> 4;
  const int row  = blockIdx.x * 64 + w * 16 + lid;
  const bool rowok = row < NN;
  const int rowv = rowok ? row : NN - 1;
  const int K = KS * 32;

  bf16x8 bfr[KS];
  const float* ap = A + (size_t)rowv * K + lg * 8;
#pragma unroll
  for (int ks = 0; ks < KS; ++ks) {
    const float4 v0 = *(const float4*)(ap + ks * 32);
    const float4 v1 = *(const float4*)(ap + ks * 32 + 4);
    bf16x8 b;
    b[0]=f2bf(v0.x); b[1]=f2bf(v0.y); b[2]=f2bf(v0.z); b[3]=f2bf(v0.w);
    b[4]=f2bf(v1.x); b[5]=f2bf(v1.y); b[6]=f2bf(v1.z); b[7]=f2bf(v1.w);
    bfr[ks] = b;
  }

  f32x4 acc[16];
#pragma unroll
  for (int n = 0; n < 16; ++n) acc[n] = (f32x4){0.f, 0.f, 0.f, 0.f};

#pragma unroll
  for (int ks = 0; ks < KS; ++ks) {
#pragma unroll
    for (int n = 0; n < 16; ++n) {
      const bf16x8 a = *(const bf16x8*)(wf + ((size_t)(ks * 16 + n) * 64 + l) * 8);
      acc[n] = __builtin_amdgcn_mfma_f32_16x16x32_bf16(a, bfr[ks], acc[n], 0, 0, 0);
    }
  }

  if (rowok) {
#pragma unroll
    for (int n = 0; n < 16; ++n) {
      const int c0 = n * 16 + lg * 4;
      const float4 bv = *(const float4*)(bias + c0);
      ushort4 o;
      o.x = f2bf(acc[n][0] + bv.x); o.y = f2bf(acc[n][1] + bv.y);
      o.z = f2bf(acc[n][2] + bv.z); o.w = f2bf(acc[n][3] + bv.w);
      *(ushort4*)(outb + (size_t)row * 256 + c0) = o;
    }
  }
}

// ---------------------------------------------------------------------------
// WeT prep: wet[c*64+k] = bf16(We[k*256+c]).
// ---------------------------------------------------------------------------
__global__ __launch_bounds__(256)
void conv_wet(const float* __restrict__ We1, unsigned short* __restrict__ wet1,
              const float* __restrict__ We2, unsigned short* __restrict__ wet2) {
  const float* We = blockIdx.y ? We2 : We1;
  unsigned short* wet = blockIdx.y ? wet2 : wet1;
  const int idx = blockIdx.x * 256 + threadIdx.x;
  const int k = idx >> 8, c = idx & 255;
  wet[c * 64 + k] = f2bf(We[(size_t)k * 256 + c]);
}

// ---------------------------------------------------------------------------
// CSR build
// ---------------------------------------------------------------------------
__global__ __launch_bounds__(256)
void dst_hist(const int* __restrict__ dst, int* __restrict__ cnt) {
  const int e = blockIdx.x * 256 + threadIdx.x;
  if (e < NE) atomicAdd(&cnt[dst[e]], 1);
}

__global__ __launch_bounds__(1024)
void exscan(int* __restrict__ cnt, int* __restrict__ row_start,
            int* __restrict__ cur, int n) {
  __shared__ int buf[1024];
  __shared__ int carry;
  if (threadIdx.x == 0) carry = 0;
  __syncthreads();
  for (int base = 0; base < n; base += 1024) {
    const int i = base + threadIdx.x;
    const int v = (i < n) ? cnt[i] : 0;
    buf[threadIdx.x] = v;
    __syncthreads();
    for (int off = 1; off < 1024; off <<= 1) {
      const int t = (threadIdx.x >= off) ? buf[threadIdx.x - off] : 0;
      __syncthreads();
      buf[threadIdx.x] += t;
      __syncthreads();
    }
    const int excl = buf[threadIdx.x] - v + carry;
    if (i < n) { row_start[i] = excl; cur[i] = excl; }
    __syncthreads();
    if (threadIdx.x == 1023) carry += buf[1023];
    __syncthreads();
  }
  if (threadIdx.x == 0) row_start[n] = carry;
}

__global__ __launch_bounds__(256)
void bucket_fill(const int* __restrict__ src, const int* __restrict__ dst,
                 int* __restrict__ cur, int* __restrict__ eid,
                 int* __restrict__ ssrc, int* __restrict__ sdst) {
  const int e = blockIdx.x * 256 + threadIdx.x;
  if (e < NE) {
    const int d = dst[e];
    const int p = atomicAdd(&cur[d], 1);
    eid[p] = e;
    ssrc[p] = src[e];
    sdst[p] = d;
  }
}

// ---------------------------------------------------------------------------
// eab prep: eab[p][c] = bf16(ea[eid[p]][c]).
// ---------------------------------------------------------------------------
__global__ __launch_bounds__(256)
void conv_eab(const float* __restrict__ ea, const int* __restrict__ eid,
              unsigned short* __restrict__ eab) {
  const int g = blockIdx.x * 256 + threadIdx.x;
  const int p = g >> 4, c4 = (g & 15) * 4;
  const int e = eid[p];
  const float4 v = *(const float4*)(ea + (size_t)e * 64 + c4);
  ushort4 o;
  o.x = f2bf(v.x); o.y = f2bf(v.y); o.z = f2bf(v.z); o.w = f2bf(v.w);
  *(ushort4*)(eab + (size_t)p * 64 + c4) = o;
}

// ---------------------------------------------------------------------------
// Edge kernel: swapped-operand MFMA with PERMUTED column mapping.
// MFMA n's A-rows are physical We-cols (i>>2)*64 + n*4 + (i&3), so lane
// (lid,lg) owns cols [lg*64 + n*4 .. +3] -> its 64 cols are the contiguous
// 128B range [lg*64, lg*64+64) = one cache line per (edge, table), loaded
// as 8 x uint4. Entire range is head lg -> logit completes lane-locally,
// no shfl reduce. Block = 128 CSR positions, 4 waves x 32 edges.
// ---------------------------------------------------------------------------
template <int EAB>
__global__ __launch_bounds__(256)
void edge_logits_swap(const float* __restrict__ ea,
                      const unsigned short* __restrict__ eab,
                      const unsigned short* __restrict__ wet,  // [256][64]
                      const unsigned short* __restrict__ xlb,
                      const unsigned short* __restrict__ xrb,
                      const float* __restrict__ att,
                      const int* __restrict__ eid,
                      const int* __restrict__ ssrc, const int* __restrict__ sdst,
                      float* __restrict__ elog) {
  __shared__ unsigned short smw[2][16][64][8];   // 32 KB

  const int tid = threadIdx.x;
  // stage: dest unit = i*256+tid (linear, conflict-free); source row is the
  // PERMUTED physical We-col: (lid_>>2)*64 + n*4 + (lid_&3)
#pragma unroll
  for (int i = 0; i < 8; ++i) {
    const int unit = i * 256 + tid;
    const int lane = unit & 63;
    const int n    = (unit >> 6) & 15;
    const int half = unit >> 10;
    const int lid_ = lane & 15, lg_ = lane >> 4;
    const int crow = (lid_ >> 2) * 64 + n * 4 + (lid_ & 3);
    const uint4 v = *(const uint4*)(wet + (size_t)crow * 64 +
                                    (half * 4 + lg_) * 8);
    *(uint4*)&smw[half][n][lane][0] = v;
  }
  __syncthreads();

  const int w = tid >> 6, l = tid & 63;
  const int lid = l & 15, lg = l >> 4;
  const int base = blockIdx.x * 128 + w * 32;
  const int pA = base + lid;
  const int pB = base + 16 + lid;
  const int sA = ssrc[pA], dA = sdst[pA];
  const int sB = ssrc[pB], dB = sdst[pB];

  bf16x8 fA0, fA1, fB0, fB1;
  if (EAB) {
    fA0 = *(const bf16x8*)(eab + (size_t)pA * 64 + lg * 8);
    fA1 = *(const bf16x8*)(eab + (size_t)pA * 64 + 32 + lg * 8);
    fB0 = *(const bf16x8*)(eab + (size_t)pB * 64 + lg * 8);
    fB1 = *(const bf16x8*)(eab + (size_t)pB * 64 + 32 + lg * 8);
  } else {
    const int eA = eid[pA], eB = eid[pB];
    const float* apA = ea + (size_t)eA * 64 + lg * 8;
    const float* apB = ea + (size_t)eB * 64 + lg * 8;
#pragma unroll
    for (int g2 = 0; g2 < 2; ++g2) {
      const float* ap = g2 ? apB : apA;
      const float4 v00 = *(const float4*)(ap);
      const float4 v01 = *(const float4*)(ap + 4);
      const float4 v10 = *(const float4*)(ap + 32);
      const float4 v11 = *(const float4*)(ap + 36);
      bf16x8 t0, t1;
      t0[0]=f2bf(v00.x); t0[1]=f2bf(v00.y); t0[2]=f2bf(v00.z); t0[3]=f2bf(v00.w);
      t0[4]=f2bf(v01.x); t0[5]=f2bf(v01.y); t0[6]=f2bf(v01.z); t0[7]=f2bf(v01.w);
      t1[0]=f2bf(v10.x); t1[1]=f2bf(v10.y); t1[2]=f2bf(v10.z); t1[3]=f2bf(v10.w);
      t1[4]=f2bf(v11.x); t1[5]=f2bf(v11.y); t1[6]=f2bf(v11.z); t1[7]=f2bf(v11.w);
      if (g2) { fB0 = t0; fB1 = t1; } else { fA0 = t0; fA1 = t1; }
    }
  }

  // my column base: head lg, cols [lg*64, lg*64+64)
  const unsigned short* xlpA = xlb + (size_t)sA * 256 + lg * 64;
  const unsigned short* xrpA = xrb + (size_t)dA * 256 + lg * 64;
  const unsigned short* xlpB = xlb + (size_t)sB * 256 + lg * 64;
  const unsigned short* xrpB = xrb + (size_t)dB * 256 + lg * 64;
  const float* attp = att + lg * 64;

  float phA = 0.f, phB = 0.f;
#pragma unroll
  for (int nn = 0; nn < 8; ++nn) {        // n pair (2nn, 2nn+1) -> 8 cols
    const bf16x8 w00 = *(const bf16x8*)&smw[0][2 * nn][l][0];
    const bf16x8 w01 = *(const bf16x8*)&smw[1][2 * nn][l][0];
    const bf16x8 w10 = *(const bf16x8*)&smw[0][2 * nn + 1][l][0];
    const bf16x8 w11 = *(const bf16x8*)&smw[1][2 * nn + 1][l][0];

    f32x4 aA0 = (f32x4){0.f,0.f,0.f,0.f}, aA1 = (f32x4){0.f,0.f,0.f,0.f};
    f32x4 aB0 = (f32x4){0.f,0.f,0.f,0.f}, aB1 = (f32x4){0.f,0.f,0.f,0.f};
    aA0 = __builtin_amdgcn_mfma_f32_16x16x32_bf16(w00, fA0, aA0, 0, 0, 0);
    aA0 = __builtin_amdgcn_mfma_f32_16x16x32_bf16(w01, fA1, aA0, 0, 0, 0);
    aA1 = __builtin_amdgcn_mfma_f32_16x16x32_bf16(w10, fA0, aA1, 0, 0, 0);
    aA1 = __builtin_amdgcn_mfma_f32_16x16x32_bf16(w11, fA1, aA1, 0, 0, 0);
    aB0 = __builtin_amdgcn_mfma_f32_16x16x32_bf16(w00, fB0, aB0, 0, 0, 0);
    aB0 = __builtin_amdgcn_mfma_f32_16x16x32_bf16(w01, fB1, aB0, 0, 0, 0);
    aB1 = __builtin_amdgcn_mfma_f32_16x16x32_bf16(w10, fB0, aB1, 0, 0, 0);
    aB1 = __builtin_amdgcn_mfma_f32_16x16x32_bf16(w11, fB1, aB1, 0, 0, 0);

    const int c0 = nn * 8;
    const float4 at0 = *(const float4*)(attp + c0);
    const float4 at1 = *(const float4*)(attp + c0 + 4);
    float v;
    {
      const uint4 xu = *(const uint4*)(xlpA + c0);
      const uint4 ru = *(const uint4*)(xrpA + c0);
      v = aA0[0] + bflo(xu.x) + bflo(ru.x); v = LRELU(v); phA += v * at0.x;
      v = aA0[1] + bfhi(xu.x) + bfhi(ru.x); v = LRELU(v); phA += v * at0.y;
      v = aA0[2] + bflo(xu.y) + bflo(ru.y); v = LRELU(v); phA += v * at0.z;
      v = aA0[3] + bfhi(xu.y) + bfhi(ru.y); v = LRELU(v); phA += v * at0.w;
      v = aA1[0] + bflo(xu.z) + bflo(ru.z); v = LRELU(v); phA += v * at1.x;
      v = aA1[1] + bfhi(xu.z) + bfhi(ru.z); v = LRELU(v); phA += v * at1.y;
      v = aA1[2] + bflo(xu.w) + bflo(ru.w); v = LRELU(v); phA += v * at1.z;
      v = aA1[3] + bfhi(xu.w) + bfhi(ru.w); v = LRELU(v); phA += v * at1.w;
    }
    {
      const uint4 xu = *(const uint4*)(xlpB + c0);
      const uint4 ru = *(const uint4*)(xrpB + c0);
      v = aB0[0] + bflo(xu.x) + bflo(ru.x); v = LRELU(v); phB += v * at0.x;
      v = aB0[1] + bfhi(xu.x) + bfhi(ru.x); v = LRELU(v); phB += v * at0.y;
      v = aB0[2] + bflo(xu.y) + bflo(ru.y); v = LRELU(v); phB += v * at0.z;
      v = aB0[3] + bfhi(xu.y) + bfhi(ru.y); v = LRELU(v); phB += v * at0.w;
      v = aB1[0] + bflo(xu.z) + bflo(ru.z); v = LRELU(v); phB += v * at1.x;
      v = aB1[1] + bfhi(xu.z) + bfhi(ru.z); v = LRELU(v); phB += v * at1.y;
      v = aB1[2] + bflo(xu.w) + bflo(ru.w); v = LRELU(v); phB += v * at1.z;
      v = aB1[3] + bfhi(xu.w) + bfhi(ru.w); v = LRELU(v); phB += v * at1.w;
    }
  }

  // lane (lid,lg) holds complete logit for (edge, head lg) — no reduce
  elog[(size_t)pA * 4 + lg] = expf(phA);
  elog[(size_t)pB * 4 + lg] = expf(phB);
}

// ---------------------------------------------------------------------------
// Aggregation: one wave per dst node, 4 nodes/block; streams CSR bucket.
// ---------------------------------------------------------------------------
__global__ __launch_bounds__(256)
void aggregate(const unsigned short* __restrict__ xlb,
               const float* __restrict__ elog,
               const int* __restrict__ ssrc, const int* __restrict__ row_start,
               const float* __restrict__ bias, float* __restrict__ out) {
  const int wid  = threadIdx.x >> 6;
  const int lane = threadIdx.x & 63;
  const int d    = blockIdx.x * 4 + wid;
  const int h = lane >> 4;
  const int c = lane * 4;
  float ax = 0.f, ay = 0.f, az = 0.f, aw = 0.f;
  float dtot = 0.f;
  const int beg = row_start[d], end = row_start[d + 1];
  for (int p = beg; p < end; ++p) {
    const float ev = elog[(size_t)p * 4 + h];
    const int s = ssrc[p];
    const uint2 xv = *(const uint2*)(xlb + (size_t)s * 256 + c);
    ax += ev * bflo(xv.x); ay += ev * bfhi(xv.x);
    az += ev * bflo(xv.y); aw += ev * bfhi(xv.y);
    dtot += ev;
  }
  const float inv = 1.f / (dtot + 1e-16f);
  const float4 bv = *(const float4*)(bias + c);
  float4 o;
  o.x = bv.x + ax * inv; o.y = bv.y + ay * inv;
  o.z = bv.z + az * inv; o.w = bv.w + aw * inv;
  *(float4*)(out + (size_t)d * 256 + c) = o;
}

extern "C" void kernel_launch(void* const* d_in, const int* in_sizes, int n_in,
                              void* d_out, int out_size, void* d_ws, size_t ws_size,
                              hipStream_t stream) {
  const float* x    = (const float*)d_in[0];
  const int*   ei   = (const int*)d_in[1];
  const float* ea   = (const float*)d_in[2];
  const float* Wl1  = (const float*)d_in[3];
  const float* bl1  = (const float*)d_in[4];
  const float* Wr1  = (const float*)d_in[5];
  const float* br1  = (const float*)d_in[6];
  const float* We1  = (const float*)d_in[7];
  const float* att1 = (const float*)d_in[8];
  const float* bias1= (const float*)d_in[9];
  const float* Wl2  = (const float*)d_in[10];
  const float* bl2  = (const float*)d_in[11];
  const float* Wr2  = (const float*)d_in[12];
  const float* br2  = (const float*)d_in[13];
  const float* We2  = (const float*)d_in[14];
  const float* att2 = (const float*)d_in[15];
  const float* bias2= (const float*)d_in[16];

  float* out = (float*)d_out;
  float* ws  = (float*)d_ws;

  float* elog = ws;                                    // NE*4 f32
  unsigned short* xlb  = (unsigned short*)(elog + (size_t)NE * 4); // NN*256
  unsigned short* xrb  = xlb + (size_t)NN * 256;       // NN*256
  unsigned short* wet1 = xrb + (size_t)NN * 256;       // 16384
  unsigned short* wet2 = wet1 + 16384;                 // 16384
  unsigned short* wlf1 = wet2 + 16384;                 // 32768
  unsigned short* wrf1 = wlf1 + 32768;                 // 32768
  unsigned short* wlf2 = wrf1 + 32768;                 // 65536
  unsigned short* wrf2 = wlf2 + 65536;                 // 65536
  int* cur       = (int*)(wrf2 + 65536);               // NN
  int* row_start = cur + NN;                           // NN+1
  int* eid       = row_start + NN + 1;                 // NE
  int* ssrc      = eid + NE;                           // NE
  int* sdst      = ssrc + NE;                          // NE
  unsigned short* eab = (unsigned short*)(sdst + NE);  // NE*64 bf16 (optional)
  const size_t need_eab =
      ((char*)(eab + (size_t)NE * 64)) - (char*)d_ws;
  const bool use_eab = ws_size >= need_eab;
  float* h1 = out;  // d_out doubles as h1

  const int* src = ei;
  const int* dst = ei + NE;

  const dim3 ggrid((NN + 63) / 64, 2);   // 782 x 2
  const int  egrid = NE / 128;           // 6250
  const int  epb   = (NE + 255) / 256;
  const int  agrid = NN / 4;             // 12500

  // ---- prep: CSR + bf16 weight tables (+ eab) ----
  hipMemsetAsync(cur, 0, NN * sizeof(int), stream);
  conv_wet<<<dim3(64, 2), 256, 0, stream>>>(We1, wet1, We2, wet2);
  conv_wf<<<128, 256, 0, stream>>>(Wl1, wlf1, 128);
  conv_wf<<<128, 256, 0, stream>>>(Wr1, wrf1, 128);
  conv_wf<<<256, 256, 0, stream>>>(Wl2, wlf2, 256);
  conv_wf<<<256, 256, 0, stream>>>(Wr2, wrf2, 256);
  dst_hist<<<epb, 256, 0, stream>>>(dst, cur);
  exscan<<<1, 1024, 0, stream>>>(cur, row_start, cur, NN);
  bucket_fill<<<epb, 256, 0, stream>>>(src, dst, cur, eid, ssrc, sdst);
  if (use_eab)
    conv_eab<<<NE * 16 / 256, 256, 0, stream>>>(ea, eid, eab);

  // ---- layer 1 ----
  gemm_mfma<4><<<ggrid, 256, 0, stream>>>(x, wlf1, bl1, xlb, wrf1, br1, xrb);
  if (use_eab)
    edge_logits_swap<1><<<egrid, 256, 0, stream>>>(ea, eab, wet1, xlb, xrb,
                                                   att1, eid, ssrc, sdst, elog);
  else
    edge_logits_swap<0><<<egrid, 256, 0, stream>>>(ea, eab, wet1, xlb, xrb,
                                                   att1, eid, ssrc, sdst, elog);
  aggregate<<<agrid, 256, 0, stream>>>(xlb, elog, ssrc, row_start, bias1, h1);

  // ---- layer 2 ----
  gemm_mfma<8><<<ggrid, 256, 0, stream>>>(h1, wlf2, bl2, xlb, wrf2, br2, xrb);
  if (use_eab)
    edge_logits_swap<1><<<egrid, 256, 0, stream>>>(ea, eab, wet2, xlb, xrb,
                                                   att2, eid, ssrc, sdst, elog);
  else
    edge_logits_swap<0><<<egrid, 256, 0, stream>>>(ea, eab, wet2, xlb, xrb,
                                                   att2, eid, ssrc, sdst, elog);
  aggregate<<<agrid, 256, 0, stream>>>(xlb, elog, ssrc, row_start, bias2, out);
}

// Round 12
// 801.661 us; speedup vs baseline: 1.1627x; 1.1627x over previous
//
#include <hip/hip_runtime.h>
#include <math.h>

#define NN 50000
#define NE 800000

#define LRELU(v) ((v) > 0.f ? (v) : 0.2f * (v))

typedef __attribute__((ext_vector_type(4))) float f32x4;
typedef __attribute__((ext_vector_type(8))) short bf16x8;

static __device__ __forceinline__ unsigned short f2bf(float f) {
  union { float f; unsigned int i; } c; c.f = f;
  unsigned int r = c.i + 0x7fff + ((c.i >> 16) & 1);   // RNE
  return (unsigned short)(r >> 16);
}
static __device__ __forceinline__ float bflo(unsigned int u) {
  union { unsigned int i; float f; } c; c.i = u << 16; return c.f;
}
static __device__ __forceinline__ float bfhi(unsigned int u) {
  union { unsigned int i; float f; } c; c.i = u & 0xffff0000u; return c.f;
}

// ---------------------------------------------------------------------------
// conv_wf: W [K][256] fp32 -> fragment-ordered bf16 table (node GEMM A-frags)
// ---------------------------------------------------------------------------
__global__ __launch_bounds__(256)
void conv_wf(const float* __restrict__ W, unsigned short* __restrict__ wf,
             int K) {
  const int g = blockIdx.x * 256 + threadIdx.x;   // K*256 total
  if (g >= K * 256) return;
  const int j = g & 7;
  const int l = (g >> 3) & 63;
  const int fn = g >> 9;
  const int n = fn & 15, ks = fn >> 4;
  const int k = ks * 32 + (l >> 4) * 8 + j;
  const int c = n * 16 + (l & 15);
  wf[g] = f2bf(W[(size_t)k * 256 + c]);
}

// ---------------------------------------------------------------------------
// conv_wef: We [64][256] -> edge-kernel fragment table (R11 permuted mapping)
//   wef[((half*16+n)*64 + l)*8 + j] =
//     bf16(We[half*32 + (l>>4)*8 + j][((l&15)>>2)*64 + n*4 + (l&3)])
// ---------------------------------------------------------------------------
__global__ __launch_bounds__(256)
void conv_wef(const float* __restrict__ We1, unsigned short* __restrict__ wef1,
              const float* __restrict__ We2, unsigned short* __restrict__ wef2) {
  const float* We = blockIdx.y ? We2 : We1;
  unsigned short* wef = blockIdx.y ? wef2 : wef1;
  const int g = blockIdx.x * 256 + threadIdx.x;   // 16384 total
  const int j = g & 7;
  const int l = (g >> 3) & 63;
  const int t = g >> 9;
  const int n = t & 15, half = t >> 4;
  const int k = half * 32 + (l >> 4) * 8 + j;
  const int c = ((l & 15) >> 2) * 64 + n * 4 + (l & 3);
  wef[g] = f2bf(We[(size_t)k * 256 + c]);
}

// ---------------------------------------------------------------------------
// MFMA node GEMM: outb = bf16(A @ W + b). No LDS; wf streamed from L1/L2.
// ---------------------------------------------------------------------------
template <int KS>   // KS = K/32
__global__ __launch_bounds__(256)
void gemm_mfma(const float* __restrict__ A,
               const unsigned short* __restrict__ wf0,
               const float* __restrict__ b0, unsigned short* __restrict__ outb0,
               const unsigned short* __restrict__ wf1,
               const float* __restrict__ b1, unsigned short* __restrict__ outb1) {
  const unsigned short* wf = blockIdx.y ? wf1 : wf0;
  const float* bias        = blockIdx.y ? b1 : b0;
  unsigned short* outb     = blockIdx.y ? outb1 : outb0;

  const int tid = threadIdx.x;
  const int w = tid >> 6, l = tid & 63;
  const int lid = l & 15, lg = l >> 4;
  const int row  = blockIdx.x * 64 + w * 16 + lid;
  const bool rowok = row < NN;
  const int rowv = rowok ? row : NN - 1;
  const int K = KS * 32;

  bf16x8 bfr[KS];
  const float* ap = A + (size_t)rowv * K + lg * 8;
#pragma unroll
  for (int ks = 0; ks < KS; ++ks) {
    const float4 v0 = *(const float4*)(ap + ks * 32);
    const float4 v1 = *(const float4*)(ap + ks * 32 + 4);
    bf16x8 b;
    b[0]=f2bf(v0.x); b[1]=f2bf(v0.y); b[2]=f2bf(v0.z); b[3]=f2bf(v0.w);
    b[4]=f2bf(v1.x); b[5]=f2bf(v1.y); b[6]=f2bf(v1.z); b[7]=f2bf(v1.w);
    bfr[ks] = b;
  }

  f32x4 acc[16];
#pragma unroll
  for (int n = 0; n < 16; ++n) acc[n] = (f32x4){0.f, 0.f, 0.f, 0.f};

#pragma unroll
  for (int ks = 0; ks < KS; ++ks) {
#pragma unroll
    for (int n = 0; n < 16; ++n) {
      const bf16x8 a = *(const bf16x8*)(wf + ((size_t)(ks * 16 + n) * 64 + l) * 8);
      acc[n] = __builtin_amdgcn_mfma_f32_16x16x32_bf16(a, bfr[ks], acc[n], 0, 0, 0);
    }
  }

  if (rowok) {
#pragma unroll
    for (int n = 0; n < 16; ++n) {
      const int c0 = n * 16 + lg * 4;
      const float4 bv = *(const float4*)(bias + c0);
      ushort4 o;
      o.x = f2bf(acc[n][0] + bv.x); o.y = f2bf(acc[n][1] + bv.y);
      o.z = f2bf(acc[n][2] + bv.z); o.w = f2bf(acc[n][3] + bv.w);
      *(ushort4*)(outb + (size_t)row * 256 + c0) = o;
    }
  }
}

// ---------------------------------------------------------------------------
// CSR build
// ---------------------------------------------------------------------------
__global__ __launch_bounds__(256)
void dst_hist(const int* __restrict__ dst, int* __restrict__ cnt) {
  const int e = blockIdx.x * 256 + threadIdx.x;
  if (e < NE) atomicAdd(&cnt[dst[e]], 1);
}

// shfl-based exclusive scan: 4 barriers/chunk instead of ~21
__global__ __launch_bounds__(1024)
void exscan(int* __restrict__ cnt, int* __restrict__ row_start,
            int* __restrict__ cur, int n) {
  __shared__ int wsum[16];
  __shared__ int woff[16];
  __shared__ int carry_s;
  const int tid = threadIdx.x;
  const int lane = tid & 63, wid = tid >> 6;
  if (tid == 0) carry_s = 0;
  __syncthreads();
  for (int base = 0; base < n; base += 1024) {
    const int i = base + tid;
    const int v = (i < n) ? cnt[i] : 0;
    int incl = v;
#pragma unroll
    for (int off = 1; off < 64; off <<= 1) {
      const int t = __shfl_up(incl, off);
      if (lane >= off) incl += t;
    }
    if (lane == 63) wsum[wid] = incl;
    __syncthreads();
    if (wid == 0) {
      const int s = (lane < 16) ? wsum[lane] : 0;
      int si = s;
#pragma unroll
      for (int off = 1; off < 16; off <<= 1) {
        const int t = __shfl_up(si, off);
        if (lane >= off) si += t;
      }
      if (lane < 16) woff[lane] = si - s;   // exclusive wave offsets
    }
    __syncthreads();
    const int excl = carry_s + woff[wid] + incl - v;
    if (i < n) { row_start[i] = excl; cur[i] = excl; }
    __syncthreads();
    if (tid == 1023) carry_s += woff[15] + wsum[15];
    __syncthreads();
  }
  if (tid == 0) row_start[n] = carry_s;
}

__global__ __launch_bounds__(256)
void bucket_fill(const int* __restrict__ src, const int* __restrict__ dst,
                 int* __restrict__ cur, int* __restrict__ eid,
                 int* __restrict__ ssrc, int* __restrict__ sdst) {
  const int e = blockIdx.x * 256 + threadIdx.x;
  if (e < NE) {
    const int d = dst[e];
    const int p = atomicAdd(&cur[d], 1);
    eid[p] = e;
    ssrc[p] = src[e];
    sdst[p] = d;
  }
}

// ---------------------------------------------------------------------------
// eab prep: eab[p][c] = bf16(ea[eid[p]][c]).
// ---------------------------------------------------------------------------
__global__ __launch_bounds__(256)
void conv_eab(const float* __restrict__ ea, const int* __restrict__ eid,
              unsigned short* __restrict__ eab) {
  const int g = blockIdx.x * 256 + threadIdx.x;
  const int p = g >> 4, c4 = (g & 15) * 4;
  const int e = eid[p];
  const float4 v = *(const float4*)(ea + (size_t)e * 64 + c4);
  ushort4 o;
  o.x = f2bf(v.x); o.y = f2bf(v.y); o.z = f2bf(v.z); o.w = f2bf(v.w);
  *(ushort4*)(eab + (size_t)p * 64 + c4) = o;
}

// ---------------------------------------------------------------------------
// Edge kernel: swapped-operand MFMA, permuted col mapping (lane-local logit).
// 16 edges/wave, 4 waves/block. Wave cooperatively stages its 16 xl rows into
// wave-private LDS (8 fully-coalesced 16B loads: 2 rows/instr, 8 lines/instr)
// -> epilogue reads LDS at the b128 BW floor. wet frags come from a
// fragment-ordered global table wef (32KB, L1-resident, lane-linear reads).
// No __syncthreads (wave-private LDS, in-order DS unit).
// ---------------------------------------------------------------------------
template <int EAB>
__global__ __launch_bounds__(256)
void edge_logits_swap(const float* __restrict__ ea,
                      const unsigned short* __restrict__ eab,
                      const unsigned short* __restrict__ wef,  // [2][16][64][8]
                      const unsigned short* __restrict__ xlb,
                      const unsigned short* __restrict__ xrb,
                      const float* __restrict__ att,
                      const int* __restrict__ eid,
                      const int* __restrict__ ssrc, const int* __restrict__ sdst,
                      float* __restrict__ elog) {
  __shared__ unsigned short sxl[4][16 * 264];   // pitch 264 ushorts (33 units)

  const int tid = threadIdx.x;
  const int w = tid >> 6, l = tid & 63;
  const int lid = l & 15, lg = l >> 4;
  const int p0 = (blockIdx.x * 4 + w) * 16;
  const int p  = p0 + lid;
  const int d  = sdst[p];

  unsigned short* myxl = sxl[w];

  // cooperative stage: instr i loads rows {2i, 2i+1}, lane -> (row, unit)
#pragma unroll
  for (int i = 0; i < 8; ++i) {
    const int row  = i * 2 + (l >> 5);
    const int unit = l & 31;
    const int srow = ssrc[p0 + row];
    const uint4 v = *(const uint4*)(xlb + (size_t)srow * 256 + unit * 8);
    *(uint4*)&myxl[row * 264 + unit * 8] = v;
  }

  // B-frags: edge p's ea row (k = 32*half + lg*8 + j)
  bf16x8 f0, f1;
  if (EAB) {
    f0 = *(const bf16x8*)(eab + (size_t)p * 64 + lg * 8);
    f1 = *(const bf16x8*)(eab + (size_t)p * 64 + 32 + lg * 8);
  } else {
    const int e = eid[p];
    const float* ap = ea + (size_t)e * 64 + lg * 8;
    const float4 v00 = *(const float4*)(ap);
    const float4 v01 = *(const float4*)(ap + 4);
    const float4 v10 = *(const float4*)(ap + 32);
    const float4 v11 = *(const float4*)(ap + 36);
    f0[0]=f2bf(v00.x); f0[1]=f2bf(v00.y); f0[2]=f2bf(v00.z); f0[3]=f2bf(v00.w);
    f0[4]=f2bf(v01.x); f0[5]=f2bf(v01.y); f0[6]=f2bf(v01.z); f0[7]=f2bf(v01.w);
    f1[0]=f2bf(v10.x); f1[1]=f2bf(v10.y); f1[2]=f2bf(v10.z); f1[3]=f2bf(v10.w);
    f1[4]=f2bf(v11.x); f1[5]=f2bf(v11.y); f1[6]=f2bf(v11.z); f1[7]=f2bf(v11.w);
  }

  // my 64 cols: head lg, range [lg*64, lg*64+64)
  const unsigned short* xlp  = myxl + lid * 264 + lg * 64;   // LDS
  const unsigned short* xrp  = xrb + (size_t)d * 256 + lg * 64;
  const float* attp = att + lg * 64;

  float ph = 0.f;
#pragma unroll
  for (int nn = 0; nn < 8; ++nn) {        // n pair (2nn, 2nn+1) -> 8 cols
    const bf16x8 w00 = *(const bf16x8*)(wef + ((size_t)(0  + 2 * nn)     * 64 + l) * 8);
    const bf16x8 w01 = *(const bf16x8*)(wef + ((size_t)(16 + 2 * nn)     * 64 + l) * 8);
    const bf16x8 w10 = *(const bf16x8*)(wef + ((size_t)(0  + 2 * nn + 1) * 64 + l) * 8);
    const bf16x8 w11 = *(const bf16x8*)(wef + ((size_t)(16 + 2 * nn + 1) * 64 + l) * 8);

    f32x4 a0 = (f32x4){0.f,0.f,0.f,0.f}, a1 = (f32x4){0.f,0.f,0.f,0.f};
    a0 = __builtin_amdgcn_mfma_f32_16x16x32_bf16(w00, f0, a0, 0, 0, 0);
    a0 = __builtin_amdgcn_mfma_f32_16x16x32_bf16(w01, f1, a0, 0, 0, 0);
    a1 = __builtin_amdgcn_mfma_f32_16x16x32_bf16(w10, f0, a1, 0, 0, 0);
    a1 = __builtin_amdgcn_mfma_f32_16x16x32_bf16(w11, f1, a1, 0, 0, 0);

    const int c0 = nn * 8;
    const uint4 xu = *(const uint4*)(xlp + c0);   // LDS, b128
    const uint4 ru = *(const uint4*)(xrp + c0);   // global, L1-hot
    const float4 at0 = *(const float4*)(attp + c0);
    const float4 at1 = *(const float4*)(attp + c0 + 4);
    float v;
    v = a0[0] + bflo(xu.x) + bflo(ru.x); v = LRELU(v); ph += v * at0.x;
    v = a0[1] + bfhi(xu.x) + bfhi(ru.x); v = LRELU(v); ph += v * at0.y;
    v = a0[2] + bflo(xu.y) + bflo(ru.y); v = LRELU(v); ph += v * at0.z;
    v = a0[3] + bfhi(xu.y) + bfhi(ru.y); v = LRELU(v); ph += v * at0.w;
    v = a1[0] + bflo(xu.z) + bflo(ru.z); v = LRELU(v); ph += v * at1.x;
    v = a1[1] + bfhi(xu.z) + bfhi(ru.z); v = LRELU(v); ph += v * at1.y;
    v = a1[2] + bflo(xu.w) + bflo(ru.w); v = LRELU(v); ph += v * at1.z;
    v = a1[3] + bfhi(xu.w) + bfhi(ru.w); v = LRELU(v); ph += v * at1.w;
  }

  // lane (lid,lg) holds the complete logit for (edge p, head lg)
  elog[(size_t)p * 4 + lg] = expf(ph);
}

// ---------------------------------------------------------------------------
// Aggregation: one wave per dst node, 4 nodes/block; 4-deep unrolled loads.
// ---------------------------------------------------------------------------
__global__ __launch_bounds__(256)
void aggregate(const unsigned short* __restrict__ xlb,
               const float* __restrict__ elog,
               const int* __restrict__ ssrc, const int* __restrict__ row_start,
               const float* __restrict__ bias, float* __restrict__ out) {
  const int wid  = threadIdx.x >> 6;
  const int lane = threadIdx.x & 63;
  const int d    = blockIdx.x * 4 + wid;
  const int h = lane >> 4;
  const int c = lane * 4;
  float ax = 0.f, ay = 0.f, az = 0.f, aw = 0.f;
  float dtot = 0.f;
  const int beg = row_start[d], end = row_start[d + 1];
  int p = beg;
  for (; p + 4 <= end; p += 4) {
    const float e0 = elog[(size_t)(p + 0) * 4 + h];
    const float e1 = elog[(size_t)(p + 1) * 4 + h];
    const float e2 = elog[(size_t)(p + 2) * 4 + h];
    const float e3 = elog[(size_t)(p + 3) * 4 + h];
    const int s0 = ssrc[p + 0], s1 = ssrc[p + 1];
    const int s2 = ssrc[p + 2], s3 = ssrc[p + 3];
    const uint2 x0 = *(const uint2*)(xlb + (size_t)s0 * 256 + c);
    const uint2 x1 = *(const uint2*)(xlb + (size_t)s1 * 256 + c);
    const uint2 x2 = *(const uint2*)(xlb + (size_t)s2 * 256 + c);
    const uint2 x3 = *(const uint2*)(xlb + (size_t)s3 * 256 + c);
    ax += e0*bflo(x0.x) + e1*bflo(x1.x) + e2*bflo(x2.x) + e3*bflo(x3.x);
    ay += e0*bfhi(x0.x) + e1*bfhi(x1.x) + e2*bfhi(x2.x) + e3*bfhi(x3.x);
    az += e0*bflo(x0.y) + e1*bflo(x1.y) + e2*bflo(x2.y) + e3*bflo(x3.y);
    aw += e0*bfhi(x0.y) + e1*bfhi(x1.y) + e2*bfhi(x2.y) + e3*bfhi(x3.y);
    dtot += e0 + e1 + e2 + e3;
  }
  for (; p < end; ++p) {
    const float ev = elog[(size_t)p * 4 + h];
    const int s = ssrc[p];
    const uint2 xv = *(const uint2*)(xlb + (size_t)s * 256 + c);
    ax += ev * bflo(xv.x); ay += ev * bfhi(xv.x);
    az += ev * bflo(xv.y); aw += ev * bfhi(xv.y);
    dtot += ev;
  }
  const float inv = 1.f / (dtot + 1e-16f);
  const float4 bv = *(const float4*)(bias + c);
  float4 o;
  o.x = bv.x + ax * inv; o.y = bv.y + ay * inv;
  o.z = bv.z + az * inv; o.w = bv.w + aw * inv;
  *(float4*)(out + (size_t)d * 256 + c) = o;
}

extern "C" void kernel_launch(void* const* d_in, const int* in_sizes, int n_in,
                              void* d_out, int out_size, void* d_ws, size_t ws_size,
                              hipStream_t stream) {
  const float* x    = (const float*)d_in[0];
  const int*   ei   = (const int*)d_in[1];
  const float* ea   = (const float*)d_in[2];
  const float* Wl1  = (const float*)d_in[3];
  const float* bl1  = (const float*)d_in[4];
  const float* Wr1  = (const float*)d_in[5];
  const float* br1  = (const float*)d_in[6];
  const float* We1  = (const float*)d_in[7];
  const float* att1 = (const float*)d_in[8];
  const float* bias1= (const float*)d_in[9];
  const float* Wl2  = (const float*)d_in[10];
  const float* bl2  = (const float*)d_in[11];
  const float* Wr2  = (const float*)d_in[12];
  const float* br2  = (const float*)d_in[13];
  const float* We2  = (const float*)d_in[14];
  const float* att2 = (const float*)d_in[15];
  const float* bias2= (const float*)d_in[16];

  float* out = (float*)d_out;
  float* ws  = (float*)d_ws;

  float* elog = ws;                                    // NE*4 f32
  unsigned short* xlb  = (unsigned short*)(elog + (size_t)NE * 4); // NN*256
  unsigned short* xrb  = xlb + (size_t)NN * 256;       // NN*256
  unsigned short* wef1 = xrb + (size_t)NN * 256;       // 16384
  unsigned short* wef2 = wef1 + 16384;                 // 16384
  unsigned short* wlf1 = wef2 + 16384;                 // 32768
  unsigned short* wrf1 = wlf1 + 32768;                 // 32768
  unsigned short* wlf2 = wrf1 + 32768;                 // 65536
  unsigned short* wrf2 = wlf2 + 65536;                 // 65536
  int* cur       = (int*)(wrf2 + 65536);               // NN
  int* row_start = cur + NN;                           // NN+1
  int* eid       = row_start + NN + 1;                 // NE
  int* ssrc      = eid + NE;                           // NE
  int* sdst      = ssrc + NE;                          // NE
  unsigned short* eab = (unsigned short*)(sdst + NE);  // NE*64 bf16 (optional)
  const size_t need_eab =
      ((char*)(eab + (size_t)NE * 64)) - (char*)d_ws;
  const bool use_eab = ws_size >= need_eab;
  float* h1 = out;  // d_out doubles as h1

  const int* src = ei;
  const int* dst = ei + NE;

  const dim3 ggrid((NN + 63) / 64, 2);   // 782 x 2
  const int  egrid = NE / 64;            // 12500 (64 positions/block)
  const int  epb   = (NE + 255) / 256;
  const int  agrid = NN / 4;             // 12500

  // ---- prep: CSR + bf16 weight tables (+ eab) ----
  hipMemsetAsync(cur, 0, NN * sizeof(int), stream);
  conv_wef<<<dim3(64, 2), 256, 0, stream>>>(We1, wef1, We2, wef2);
  conv_wf<<<128, 256, 0, stream>>>(Wl1, wlf1, 128);
  conv_wf<<<128, 256, 0, stream>>>(Wr1, wrf1, 128);
  conv_wf<<<256, 256, 0, stream>>>(Wl2, wlf2, 256);
  conv_wf<<<256, 256, 0, stream>>>(Wr2, wrf2, 256);
  dst_hist<<<epb, 256, 0, stream>>>(dst, cur);
  exscan<<<1, 1024, 0, stream>>>(cur, row_start, cur, NN);
  bucket_fill<<<epb, 256, 0, stream>>>(src, dst, cur, eid, ssrc, sdst);
  if (use_eab)
    conv_eab<<<NE * 16 / 256, 256, 0, stream>>>(ea, eid, eab);

  // ---- layer 1 ----
  gemm_mfma<4><<<ggrid, 256, 0, stream>>>(x, wlf1, bl1, xlb, wrf1, br1, xrb);
  if (use_eab)
    edge_logits_swap<1><<<egrid, 256, 0, stream>>>(ea, eab, wef1, xlb, xrb,
                                                   att1, eid, ssrc, sdst, elog);
  else
    edge_logits_swap<0><<<egrid, 256, 0, stream>>>(ea, eab, wef1, xlb, xrb,
                                                   att1, eid, ssrc, sdst, elog);
  aggregate<<<agrid, 256, 0, stream>>>(xlb, elog, ssrc, row_start, bias1, h1);

  // ---- layer 2 ----
  gemm_mfma<8><<<ggrid, 256, 0, stream>>>(h1, wlf2, bl2, xlb, wrf2, br2, xrb);
  if (use_eab)
    edge_logits_swap<1><<<egrid, 256, 0, stream>>>(ea, eab, wef2, xlb, xrb,
                                                   att2, eid, ssrc, sdst, elog);
  else
    edge_logits_swap<0><<<egrid, 256, 0, stream>>>(ea, eab, wef2, xlb, xrb,
                                                   att2, eid, ssrc, sdst, elog);
  aggregate<<<agrid, 256, 0, stream>>>(xlb, elog, ssrc, row_start, bias2, out);
}

// Round 13
// 696.066 us; speedup vs baseline: 1.3391x; 1.1517x over previous
//
#include <hip/hip_runtime.h>
#include <math.h>

#define NN 50000
#define NE 800000

#define LRELU(v) ((v) > 0.f ? (v) : 0.2f * (v))

typedef __attribute__((ext_vector_type(4))) float f32x4;
typedef __attribute__((ext_vector_type(8))) short bf16x8;

static __device__ __forceinline__ unsigned short f2bf(float f) {
  union { float f; unsigned int i; } c; c.f = f;
  unsigned int r = c.i + 0x7fff + ((c.i >> 16) & 1);   // RNE
  return (unsigned short)(r >> 16);
}
static __device__ __forceinline__ float bflo(unsigned int u) {
  union { unsigned int i; float f; } c; c.i = u << 16; return c.f;
}
static __device__ __forceinline__ float bfhi(unsigned int u) {
  union { unsigned int i; float f; } c; c.i = u & 0xffff0000u; return c.f;
}

// ---------------------------------------------------------------------------
// conv_wf: W [K][256] fp32 -> fragment-ordered bf16 table (node GEMM A-frags)
// ---------------------------------------------------------------------------
__global__ __launch_bounds__(256)
void conv_wf(const float* __restrict__ W, unsigned short* __restrict__ wf,
             int K) {
  const int g = blockIdx.x * 256 + threadIdx.x;   // K*256 total
  if (g >= K * 256) return;
  const int j = g & 7;
  const int l = (g >> 3) & 63;
  const int fn = g >> 9;
  const int n = fn & 15, ks = fn >> 4;
  const int k = ks * 32 + (l >> 4) * 8 + j;
  const int c = n * 16 + (l & 15);
  wf[g] = f2bf(W[(size_t)k * 256 + c]);
}

// ---------------------------------------------------------------------------
// conv_wef: We [64][256] -> edge-kernel fragment table (permuted mapping)
// ---------------------------------------------------------------------------
__global__ __launch_bounds__(256)
void conv_wef(const float* __restrict__ We1, unsigned short* __restrict__ wef1,
              const float* __restrict__ We2, unsigned short* __restrict__ wef2) {
  const float* We = blockIdx.y ? We2 : We1;
  unsigned short* wef = blockIdx.y ? wef2 : wef1;
  const int g = blockIdx.x * 256 + threadIdx.x;   // 16384 total
  const int j = g & 7;
  const int l = (g >> 3) & 63;
  const int t = g >> 9;
  const int n = t & 15, half = t >> 4;
  const int k = half * 32 + (l >> 4) * 8 + j;
  const int c = ((l & 15) >> 2) * 64 + n * 4 + (l & 3);
  wef[g] = f2bf(We[(size_t)k * 256 + c]);
}

// ---------------------------------------------------------------------------
// Fused MFMA node GEMM: xl = bf16(A@Wl + bl), xr = bf16(A@Wr + br).
// A row-frags loaded + converted ONCE, two sequential MFMA passes.
// ---------------------------------------------------------------------------
template <int KS>   // KS = K/32
__global__ __launch_bounds__(256)
void gemm_mfma2(const float* __restrict__ A,
                const unsigned short* __restrict__ wfl,
                const float* __restrict__ bl, unsigned short* __restrict__ outl,
                const unsigned short* __restrict__ wfr,
                const float* __restrict__ br, unsigned short* __restrict__ outr) {
  const int tid = threadIdx.x;
  const int w = tid >> 6, l = tid & 63;
  const int lid = l & 15, lg = l >> 4;
  const int row  = blockIdx.x * 64 + w * 16 + lid;
  const bool rowok = row < NN;
  const int rowv = rowok ? row : NN - 1;
  const int K = KS * 32;

  bf16x8 bfr[KS];
  const float* ap = A + (size_t)rowv * K + lg * 8;
#pragma unroll
  for (int ks = 0; ks < KS; ++ks) {
    const float4 v0 = *(const float4*)(ap + ks * 32);
    const float4 v1 = *(const float4*)(ap + ks * 32 + 4);
    bf16x8 b;
    b[0]=f2bf(v0.x); b[1]=f2bf(v0.y); b[2]=f2bf(v0.z); b[3]=f2bf(v0.w);
    b[4]=f2bf(v1.x); b[5]=f2bf(v1.y); b[6]=f2bf(v1.z); b[7]=f2bf(v1.w);
    bfr[ks] = b;
  }

  f32x4 acc[16];

  // ---- pass 1: Wl ----
#pragma unroll
  for (int n = 0; n < 16; ++n) acc[n] = (f32x4){0.f, 0.f, 0.f, 0.f};
#pragma unroll
  for (int ks = 0; ks < KS; ++ks)
#pragma unroll
    for (int n = 0; n < 16; ++n) {
      const bf16x8 a = *(const bf16x8*)(wfl + ((size_t)(ks * 16 + n) * 64 + l) * 8);
      acc[n] = __builtin_amdgcn_mfma_f32_16x16x32_bf16(a, bfr[ks], acc[n], 0, 0, 0);
    }
  if (rowok) {
#pragma unroll
    for (int n = 0; n < 16; ++n) {
      const int c0 = n * 16 + lg * 4;
      const float4 bv = *(const float4*)(bl + c0);
      ushort4 o;
      o.x = f2bf(acc[n][0] + bv.x); o.y = f2bf(acc[n][1] + bv.y);
      o.z = f2bf(acc[n][2] + bv.z); o.w = f2bf(acc[n][3] + bv.w);
      *(ushort4*)(outl + (size_t)row * 256 + c0) = o;
    }
  }

  // ---- pass 2: Wr (reuse A frags) ----
#pragma unroll
  for (int n = 0; n < 16; ++n) acc[n] = (f32x4){0.f, 0.f, 0.f, 0.f};
#pragma unroll
  for (int ks = 0; ks < KS; ++ks)
#pragma unroll
    for (int n = 0; n < 16; ++n) {
      const bf16x8 a = *(const bf16x8*)(wfr + ((size_t)(ks * 16 + n) * 64 + l) * 8);
      acc[n] = __builtin_amdgcn_mfma_f32_16x16x32_bf16(a, bfr[ks], acc[n], 0, 0, 0);
    }
  if (rowok) {
#pragma unroll
    for (int n = 0; n < 16; ++n) {
      const int c0 = n * 16 + lg * 4;
      const float4 bv = *(const float4*)(br + c0);
      ushort4 o;
      o.x = f2bf(acc[n][0] + bv.x); o.y = f2bf(acc[n][1] + bv.y);
      o.z = f2bf(acc[n][2] + bv.z); o.w = f2bf(acc[n][3] + bv.w);
      *(ushort4*)(outr + (size_t)row * 256 + c0) = o;
    }
  }
}

// ---------------------------------------------------------------------------
// CSR build
// ---------------------------------------------------------------------------
__global__ __launch_bounds__(256)
void dst_hist(const int* __restrict__ dst, int* __restrict__ cnt) {
  const int e = blockIdx.x * 256 + threadIdx.x;
  if (e < NE) atomicAdd(&cnt[dst[e]], 1);
}

// 3-phase parallel exclusive scan ------------------------------------------
__global__ __launch_bounds__(1024)
void scan_bsum(const int* __restrict__ cnt, int* __restrict__ bsum, int n) {
  __shared__ int wsum[16];
  const int tid = threadIdx.x;
  const int lane = tid & 63, wid = tid >> 6;
  const int i = blockIdx.x * 1024 + tid;
  int v = (i < n) ? cnt[i] : 0;
#pragma unroll
  for (int off = 32; off >= 1; off >>= 1) v += __shfl_xor(v, off);
  if (lane == 0) wsum[wid] = v;
  __syncthreads();
  if (tid == 0) {
    int s = 0;
#pragma unroll
    for (int k = 0; k < 16; ++k) s += wsum[k];
    bsum[blockIdx.x] = s;
  }
}

__global__ __launch_bounds__(64)
void scan_bsum_scan(int* __restrict__ bsum, int* __restrict__ row_start,
                    int nb, int n) {
  const int lane = threadIdx.x;
  const int v = (lane < nb) ? bsum[lane] : 0;
  int incl = v;
#pragma unroll
  for (int off = 1; off < 64; off <<= 1) {
    const int t = __shfl_up(incl, off);
    if (lane >= off) incl += t;
  }
  if (lane < nb) bsum[lane] = incl - v;     // exclusive block offsets
  if (lane == 63) row_start[n] = incl;      // total
}

__global__ __launch_bounds__(1024)
void scan_apply(int* __restrict__ cnt, const int* __restrict__ bsum,
                int* __restrict__ row_start, int n) {
  __shared__ int wsum[16];
  __shared__ int woff[16];
  const int tid = threadIdx.x;
  const int lane = tid & 63, wid = tid >> 6;
  const int i = blockIdx.x * 1024 + tid;
  const int v = (i < n) ? cnt[i] : 0;
  int incl = v;
#pragma unroll
  for (int off = 1; off < 64; off <<= 1) {
    const int t = __shfl_up(incl, off);
    if (lane >= off) incl += t;
  }
  if (lane == 63) wsum[wid] = incl;
  __syncthreads();
  if (wid == 0) {
    const int s = (lane < 16) ? wsum[lane] : 0;
    int si = s;
#pragma unroll
    for (int off = 1; off < 16; off <<= 1) {
      const int t = __shfl_up(si, off);
      if (lane >= off) si += t;
    }
    if (lane < 16) woff[lane] = si - s;
  }
  __syncthreads();
  if (i < n) {
    const int excl = bsum[blockIdx.x] + woff[wid] + incl - v;
    row_start[i] = excl;
    cnt[i] = excl;          // becomes cursor for bucket_fill
  }
}

__global__ __launch_bounds__(256)
void bucket_fill(const int* __restrict__ src, const int* __restrict__ dst,
                 int* __restrict__ cur, int* __restrict__ eid,
                 int* __restrict__ ssrc, int* __restrict__ sdst) {
  const int e = blockIdx.x * 256 + threadIdx.x;
  if (e < NE) {
    const int d = dst[e];
    const int p = atomicAdd(&cur[d], 1);
    eid[p] = e;
    ssrc[p] = src[e];
    sdst[p] = d;
  }
}

// ---------------------------------------------------------------------------
// eab prep: eab[p][c] = bf16(ea[eid[p]][c]).
// ---------------------------------------------------------------------------
__global__ __launch_bounds__(256)
void conv_eab(const float* __restrict__ ea, const int* __restrict__ eid,
              unsigned short* __restrict__ eab) {
  const int g = blockIdx.x * 256 + threadIdx.x;
  const int p = g >> 4, c4 = (g & 15) * 4;
  const int e = eid[p];
  const float4 v = *(const float4*)(ea + (size_t)e * 64 + c4);
  ushort4 o;
  o.x = f2bf(v.x); o.y = f2bf(v.y); o.z = f2bf(v.z); o.w = f2bf(v.w);
  *(ushort4*)(eab + (size_t)p * 64 + c4) = o;
}

// ---------------------------------------------------------------------------
// Edge kernel: swapped-operand MFMA, permuted col mapping (lane-local logit),
// wave-private LDS xl staging. 128-thread blocks (2 waves) -> 16.9KB LDS ->
// 9 blocks/CU = 18 waves/CU (56% occupancy). eab frags loaded before the
// ssrc-dependent stage for MLP depth. No __syncthreads.
// ---------------------------------------------------------------------------
template <int EAB>
__global__ __launch_bounds__(128)
void edge_logits_swap(const float* __restrict__ ea,
                      const unsigned short* __restrict__ eab,
                      const unsigned short* __restrict__ wef,  // [2][16][64][8]
                      const unsigned short* __restrict__ xlb,
                      const unsigned short* __restrict__ xrb,
                      const float* __restrict__ att,
                      const int* __restrict__ eid,
                      const int* __restrict__ ssrc, const int* __restrict__ sdst,
                      float* __restrict__ elog) {
  __shared__ unsigned short sxl[2][16 * 264];   // 2 x 8448 B

  const int tid = threadIdx.x;
  const int w = tid >> 6, l = tid & 63;
  const int lid = l & 15, lg = l >> 4;
  const int p0 = (blockIdx.x * 2 + w) * 16;
  const int p  = p0 + lid;

  // B-frags first (independent of ssrc)
  bf16x8 f0, f1;
  if (EAB) {
    f0 = *(const bf16x8*)(eab + (size_t)p * 64 + lg * 8);
    f1 = *(const bf16x8*)(eab + (size_t)p * 64 + 32 + lg * 8);
  } else {
    const int e = eid[p];
    const float* ap = ea + (size_t)e * 64 + lg * 8;
    const float4 v00 = *(const float4*)(ap);
    const float4 v01 = *(const float4*)(ap + 4);
    const float4 v10 = *(const float4*)(ap + 32);
    const float4 v11 = *(const float4*)(ap + 36);
    f0[0]=f2bf(v00.x); f0[1]=f2bf(v00.y); f0[2]=f2bf(v00.z); f0[3]=f2bf(v00.w);
    f0[4]=f2bf(v01.x); f0[5]=f2bf(v01.y); f0[6]=f2bf(v01.z); f0[7]=f2bf(v01.w);
    f1[0]=f2bf(v10.x); f1[1]=f2bf(v10.y); f1[2]=f2bf(v10.z); f1[3]=f2bf(v10.w);
    f1[4]=f2bf(v11.x); f1[5]=f2bf(v11.y); f1[6]=f2bf(v11.z); f1[7]=f2bf(v11.w);
  }

  const int d = sdst[p];
  unsigned short* myxl = sxl[w];

  // cooperative stage: instr i loads rows {2i, 2i+1}, lane -> (row, unit)
#pragma unroll
  for (int i = 0; i < 8; ++i) {
    const int row  = i * 2 + (l >> 5);
    const int unit = l & 31;
    const int srow = ssrc[p0 + row];
    const uint4 v = *(const uint4*)(xlb + (size_t)srow * 256 + unit * 8);
    *(uint4*)&myxl[row * 264 + unit * 8] = v;
  }

  // my 64 cols: head lg, range [lg*64, lg*64+64)
  const unsigned short* xlp  = myxl + lid * 264 + lg * 64;   // LDS
  const unsigned short* xrp  = xrb + (size_t)d * 256 + lg * 64;
  const float* attp = att + lg * 64;

  float ph = 0.f;
#pragma unroll
  for (int nn = 0; nn < 8; ++nn) {        // n pair (2nn, 2nn+1) -> 8 cols
    const bf16x8 w00 = *(const bf16x8*)(wef + ((size_t)(0  + 2 * nn)     * 64 + l) * 8);
    const bf16x8 w01 = *(const bf16x8*)(wef + ((size_t)(16 + 2 * nn)     * 64 + l) * 8);
    const bf16x8 w10 = *(const bf16x8*)(wef + ((size_t)(0  + 2 * nn + 1) * 64 + l) * 8);
    const bf16x8 w11 = *(const bf16x8*)(wef + ((size_t)(16 + 2 * nn + 1) * 64 + l) * 8);

    f32x4 a0 = (f32x4){0.f,0.f,0.f,0.f}, a1 = (f32x4){0.f,0.f,0.f,0.f};
    a0 = __builtin_amdgcn_mfma_f32_16x16x32_bf16(w00, f0, a0, 0, 0, 0);
    a0 = __builtin_amdgcn_mfma_f32_16x16x32_bf16(w01, f1, a0, 0, 0, 0);
    a1 = __builtin_amdgcn_mfma_f32_16x16x32_bf16(w10, f0, a1, 0, 0, 0);
    a1 = __builtin_amdgcn_mfma_f32_16x16x32_bf16(w11, f1, a1, 0, 0, 0);

    const int c0 = nn * 8;
    const uint4 xu = *(const uint4*)(xlp + c0);   // LDS b128
    const uint4 ru = *(const uint4*)(xrp + c0);   // global, dst-clustered
    const float4 at0 = *(const float4*)(attp + c0);
    const float4 at1 = *(const float4*)(attp + c0 + 4);
    float v;
    v = a0[0] + bflo(xu.x) + bflo(ru.x); v = LRELU(v); ph += v * at0.x;
    v = a0[1] + bfhi(xu.x) + bfhi(ru.x); v = LRELU(v); ph += v * at0.y;
    v = a0[2] + bflo(xu.y) + bflo(ru.y); v = LRELU(v); ph += v * at0.z;
    v = a0[3] + bfhi(xu.y) + bfhi(ru.y); v = LRELU(v); ph += v * at0.w;
    v = a1[0] + bflo(xu.z) + bflo(ru.z); v = LRELU(v); ph += v * at1.x;
    v = a1[1] + bfhi(xu.z) + bfhi(ru.z); v = LRELU(v); ph += v * at1.y;
    v = a1[2] + bflo(xu.w) + bflo(ru.w); v = LRELU(v); ph += v * at1.z;
    v = a1[3] + bfhi(xu.w) + bfhi(ru.w); v = LRELU(v); ph += v * at1.w;
  }

  elog[(size_t)p * 4 + lg] = expf(ph);
}

// ---------------------------------------------------------------------------
// Aggregation: one wave per dst node, 4 nodes/block; 4-deep unrolled loads.
// ---------------------------------------------------------------------------
__global__ __launch_bounds__(256)
void aggregate(const unsigned short* __restrict__ xlb,
               const float* __restrict__ elog,
               const int* __restrict__ ssrc, const int* __restrict__ row_start,
               const float* __restrict__ bias, float* __restrict__ out) {
  const int wid  = threadIdx.x >> 6;
  const int lane = threadIdx.x & 63;
  const int d    = blockIdx.x * 4 + wid;
  const int h = lane >> 4;
  const int c = lane * 4;
  float ax = 0.f, ay = 0.f, az = 0.f, aw = 0.f;
  float dtot = 0.f;
  const int beg = row_start[d], end = row_start[d + 1];
  int p = beg;
  for (; p + 4 <= end; p += 4) {
    const float e0 = elog[(size_t)(p + 0) * 4 + h];
    const float e1 = elog[(size_t)(p + 1) * 4 + h];
    const float e2 = elog[(size_t)(p + 2) * 4 + h];
    const float e3 = elog[(size_t)(p + 3) * 4 + h];
    const int s0 = ssrc[p + 0], s1 = ssrc[p + 1];
    const int s2 = ssrc[p + 2], s3 = ssrc[p + 3];
    const uint2 x0 = *(const uint2*)(xlb + (size_t)s0 * 256 + c);
    const uint2 x1 = *(const uint2*)(xlb + (size_t)s1 * 256 + c);
    const uint2 x2 = *(const uint2*)(xlb + (size_t)s2 * 256 + c);
    const uint2 x3 = *(const uint2*)(xlb + (size_t)s3 * 256 + c);
    ax += e0*bflo(x0.x) + e1*bflo(x1.x) + e2*bflo(x2.x) + e3*bflo(x3.x);
    ay += e0*bfhi(x0.x) + e1*bfhi(x1.x) + e2*bfhi(x2.x) + e3*bfhi(x3.x);
    az += e0*bflo(x0.y) + e1*bflo(x1.y) + e2*bflo(x2.y) + e3*bflo(x3.y);
    aw += e0*bfhi(x0.y) + e1*bfhi(x1.y) + e2*bfhi(x2.y) + e3*bfhi(x3.y);
    dtot += e0 + e1 + e2 + e3;
  }
  for (; p < end; ++p) {
    const float ev = elog[(size_t)p * 4 + h];
    const int s = ssrc[p];
    const uint2 xv = *(const uint2*)(xlb + (size_t)s * 256 + c);
    ax += ev * bflo(xv.x); ay += ev * bfhi(xv.x);
    az += ev * bflo(xv.y); aw += ev * bfhi(xv.y);
    dtot += ev;
  }
  const float inv = 1.f / (dtot + 1e-16f);
  const float4 bv = *(const float4*)(bias + c);
  float4 o;
  o.x = bv.x + ax * inv; o.y = bv.y + ay * inv;
  o.z = bv.z + az * inv; o.w = bv.w + aw * inv;
  *(float4*)(out + (size_t)d * 256 + c) = o;
}

extern "C" void kernel_launch(void* const* d_in, const int* in_sizes, int n_in,
                              void* d_out, int out_size, void* d_ws, size_t ws_size,
                              hipStream_t stream) {
  const float* x    = (const float*)d_in[0];
  const int*   ei   = (const int*)d_in[1];
  const float* ea   = (const float*)d_in[2];
  const float* Wl1  = (const float*)d_in[3];
  const float* bl1  = (const float*)d_in[4];
  const float* Wr1  = (const float*)d_in[5];
  const float* br1  = (const float*)d_in[6];
  const float* We1  = (const float*)d_in[7];
  const float* att1 = (const float*)d_in[8];
  const float* bias1= (const float*)d_in[9];
  const float* Wl2  = (const float*)d_in[10];
  const float* bl2  = (const float*)d_in[11];
  const float* Wr2  = (const float*)d_in[12];
  const float* br2  = (const float*)d_in[13];
  const float* We2  = (const float*)d_in[14];
  const float* att2 = (const float*)d_in[15];
  const float* bias2= (const float*)d_in[16];

  float* out = (float*)d_out;
  float* ws  = (float*)d_ws;

  float* elog = ws;                                    // NE*4 f32
  unsigned short* xlb  = (unsigned short*)(elog + (size_t)NE * 4); // NN*256
  unsigned short* xrb  = xlb + (size_t)NN * 256;       // NN*256
  unsigned short* wef1 = xrb + (size_t)NN * 256;       // 16384
  unsigned short* wef2 = wef1 + 16384;                 // 16384
  unsigned short* wlf1 = wef2 + 16384;                 // 32768
  unsigned short* wrf1 = wlf1 + 32768;                 // 32768
  unsigned short* wlf2 = wrf1 + 32768;                 // 65536
  unsigned short* wrf2 = wlf2 + 65536;                 // 65536
  int* cur       = (int*)(wrf2 + 65536);               // NN
  int* row_start = cur + NN;                           // NN+1
  int* bsum      = row_start + NN + 1;                 // 64
  int* eid       = bsum + 64;                          // NE
  int* ssrc      = eid + NE;                           // NE
  int* sdst      = ssrc + NE;                          // NE
  unsigned short* eab = (unsigned short*)(sdst + NE);  // NE*64 bf16 (optional)
  const size_t need_eab =
      ((char*)(eab + (size_t)NE * 64)) - (char*)d_ws;
  const bool use_eab = ws_size >= need_eab;
  float* h1 = out;  // d_out doubles as h1

  const int* src = ei;
  const int* dst = ei + NE;

  const int ggrid = (NN + 63) / 64;      // 782
  const int egrid = NE / 32;             // 25000 (2 waves x 16 / block)
  const int epb   = (NE + 255) / 256;
  const int agrid = NN / 4;              // 12500
  const int nb    = (NN + 1023) / 1024;  // 49

  // ---- prep: CSR + bf16 weight tables (+ eab) ----
  hipMemsetAsync(cur, 0, NN * sizeof(int), stream);
  conv_wef<<<dim3(64, 2), 256, 0, stream>>>(We1, wef1, We2, wef2);
  conv_wf<<<128, 256, 0, stream>>>(Wl1, wlf1, 128);
  conv_wf<<<128, 256, 0, stream>>>(Wr1, wrf1, 128);
  conv_wf<<<256, 256, 0, stream>>>(Wl2, wlf2, 256);
  conv_wf<<<256, 256, 0, stream>>>(Wr2, wrf2, 256);
  dst_hist<<<epb, 256, 0, stream>>>(dst, cur);
  scan_bsum<<<nb, 1024, 0, stream>>>(cur, bsum, NN);
  scan_bsum_scan<<<1, 64, 0, stream>>>(bsum, row_start, nb, NN);
  scan_apply<<<nb, 1024, 0, stream>>>(cur, bsum, row_start, NN);
  bucket_fill<<<epb, 256, 0, stream>>>(src, dst, cur, eid, ssrc, sdst);
  if (use_eab)
    conv_eab<<<NE * 16 / 256, 256, 0, stream>>>(ea, eid, eab);

  // ---- layer 1 ----
  gemm_mfma2<4><<<ggrid, 256, 0, stream>>>(x, wlf1, bl1, xlb, wrf1, br1, xrb);
  if (use_eab)
    edge_logits_swap<1><<<egrid, 128, 0, stream>>>(ea, eab, wef1, xlb, xrb,
                                                   att1, eid, ssrc, sdst, elog);
  else
    edge_logits_swap<0><<<egrid, 128, 0, stream>>>(ea, eab, wef1, xlb, xrb,
                                                   att1, eid, ssrc, sdst, elog);
  aggregate<<<agrid, 256, 0, stream>>>(xlb, elog, ssrc, row_start, bias1, h1);

  // ---- layer 2 ----
  gemm_mfma2<8><<<ggrid, 256, 0, stream>>>(h1, wlf2, bl2, xlb, wrf2, br2, xrb);
  if (use_eab)
    edge_logits_swap<1><<<egrid, 128, 0, stream>>>(ea, eab, wef2, xlb, xrb,
                                                   att2, eid, ssrc, sdst, elog);
  else
    edge_logits_swap<0><<<egrid, 128, 0, stream>>>(ea, eab, wef2, xlb, xrb,
                                                   att2, eid, ssrc, sdst, elog);
  aggregate<<<agrid, 256, 0, stream>>>(xlb, elog, ssrc, row_start, bias2, out);
}